// Round 13
// baseline (133.535 us; speedup 1.0000x reference)
//
#include <hip/hip_runtime.h>
#include <math.h>

#define D   128
#define HP  32
#define WP  32
#define M   64
#define Bb  8
#define Tt  16
#define P   (HP*WP)      // 1024
#define BT  (Bb*Tt)      // 128
#define EPSF 1e-5f
#define SCALE 0.08838834764831845f   // 1/sqrt(128)

typedef __attribute__((ext_vector_type(8))) _Float16 half8;
typedef __attribute__((ext_vector_type(8))) short    short8;
typedef __attribute__((ext_vector_type(4))) float    floatx4;

// ---------------------------------------------------------------------------
// Prep: RoPE cos/sin table + Wq/Wk fp32->fp16.  (validated)
// ---------------------------------------------------------------------------
__global__ __launch_bounds__(1024)
void prep(const float* __restrict__ Wq, const float* __restrict__ Wk,
          _Float16* __restrict__ W16q, _Float16* __restrict__ W16k,
          float2* __restrict__ ropetab)
{
  const int b = blockIdx.x, t = threadIdx.x;
  if (b == 0) {
    const int gq = t >> 5, coord = t & 31;
    const float theta = __powf(100.0f, -4.0f*(float)(gq+1)/128.0f);
    float s, c;
    __sincosf(theta*(float)coord, &s, &c);
    ropetab[t] = make_float2(c, s);
  } else if (b <= 16) {
    const int i = (b-1)*1024 + t;
    W16q[i] = (_Float16)Wq[i];
  } else {
    const int i = (b-17)*1024 + t;
    W16k[i] = (_Float16)Wk[i];
  }
}

// ---------------------------------------------------------------------------
// One 64-row GEMM+RoPE+LN pass, registers only after W is staged.
// Byte-identical math to validated R8/R9/R10 gemm body.
// ---------------------------------------------------------------------------
template<bool IS_Q>
__device__ __forceinline__
void gemm64(const float* __restrict__ xin,
            const float* __restrict__ bvec,
            const float* __restrict__ g,
            const float* __restrict__ bln,
            const int*   __restrict__ positions,
            const float2* __restrict__ ropetab,
            _Float16* __restrict__ yout,
            const _Float16* wl, int block0)
{
  const int tid = threadIdx.x;
  const int w = tid >> 6, lane = tid & 63;
  const int gg = lane >> 4, c = lane & 15;

  const float* xr = xin + (size_t)(block0 + w*16 + c) * D;
  half8 aq[4];
  #pragma unroll
  for (int ks = 0; ks < 4; ++ks) {
    const float4 f0 = *(const float4*)(xr + ks*32 + gg*8);
    const float4 f1 = *(const float4*)(xr + ks*32 + gg*8 + 4);
    _Float16 h[8] = {(_Float16)f0.x,(_Float16)f0.y,(_Float16)f0.z,(_Float16)f0.w,
                     (_Float16)f1.x,(_Float16)f1.y,(_Float16)f1.z,(_Float16)f1.w};
    aq[ks] = *(half8*)h;
  }

  floatx4 acc[8];
  #pragma unroll
  for (int jt = 0; jt < 8; ++jt) {
    floatx4 a4 = (floatx4){0.f,0.f,0.f,0.f};
    #pragma unroll
    for (int ks = 0; ks < 4; ++ks) {
      const int brow = jt*16 + c;
      const int byte = brow*256 + (gg*8 + ks*32)*2;
      const half8 bf = *(const half8*)((const char*)wl + (byte ^ ((brow&7)<<4)));
      a4 = __builtin_amdgcn_mfma_f32_16x16x32_f16(aq[ks], bf, a4, 0, 0, 0);
    }
    acc[jt] = a4;
  }

  const int rr = c & 3;
  int coordv[4];
  #pragma unroll
  for (int r = 0; r < 4; ++r) {
    const int grow = block0 + w*16 + gg*4 + r;
    int hh, ww;
    if (IS_Q) { const int pos = positions[grow]; hh = pos >> 5; ww = pos & 31; }
    else      { const int p = grow & (P-1);      hh = p  >> 5; ww = p  & 31; }
    coordv[r] = (rr & 1) ? ww : hh;
  }

  float fin[8][4];
  float s1[4] = {0.f,0.f,0.f,0.f}, s2[4] = {0.f,0.f,0.f,0.f};
  #pragma unroll
  for (int jt = 0; jt < 8; ++jt) {
    const float bj = bvec[jt*16 + c];
    const int gq = jt*4 + (c >> 2);
    #pragma unroll
    for (int r = 0; r < 4; ++r) {
      const float val = acc[jt][r] + bj;
      const float2 tt = ropetab[gq*32 + coordv[r]];
      const float p2 = __shfl_xor(val, 2);
      const float f1v = (rr & 1) ? (val*tt.x + p2*tt.y)
                                 : (val*tt.x - p2*tt.y);
      const float g2 = __shfl_xor(f1v, 2);
      const float fn = (rr >= 2)
          ? ((rr & 1) ? (val*tt.x + g2*tt.y) : (val*tt.x - g2*tt.y))
          : f1v;
      fin[jt][r] = fn;
      s1[r] += fn;
      s2[r] += fn*fn;
    }
  }

  #pragma unroll
  for (int r = 0; r < 4; ++r) {
    #pragma unroll
    for (int off = 1; off <= 8; off <<= 1) {
      s1[r] += __shfl_xor(s1[r], off);
      s2[r] += __shfl_xor(s2[r], off);
    }
  }

  #pragma unroll
  for (int r = 0; r < 4; ++r) {
    const float mu   = s1[r] * (1.f/128.f);
    const float var  = s2[r] * (1.f/128.f) - mu*mu;
    const float rinv = rsqrtf(var + EPSF);
    const int grow = block0 + w*16 + gg*4 + r;
    _Float16* yo = yout + (size_t)grow * D;
    #pragma unroll
    for (int jt = 0; jt < 8; ++jt) {
      const int col = jt*16 + c;
      const float nv = (fin[jt][r] - mu) * rinv * g[col] + bln[col];
      yo[col] = (_Float16)nv;
    }
  }
}

// ---------------------------------------------------------------------------
// K path, 128 rows/block (1024 blocks): stage W once, two 64-row GEMM passes
// (register-only, no barrier between), then V^T of all 128 rows via the
// (now-dead) 32KB wl: restage + emit with the validated swizzle code.
// ---------------------------------------------------------------------------
__global__ __launch_bounds__(256)
void proj_k128(const float* __restrict__ mv,
               const _Float16* __restrict__ w16k,
               const float* __restrict__ bk,
               const float* __restrict__ g,
               const float* __restrict__ bln,
               const float2* __restrict__ ropetab,
               _Float16* __restrict__ kout,
               _Float16* __restrict__ vt)
{
  const int tid = threadIdx.x;
  const int block0 = blockIdx.x * 128;

  __shared__ _Float16 wl[128*128];  // W (32KB); later: 128-row mv tile

  {
    const short8* wg = (const short8*)w16k;
    #pragma unroll
    for (int it = 0; it < 8; ++it) {
      const int idx = tid + 256*it;
      const int row = idx >> 4, col8 = idx & 15;
      const short8 v = wg[idx];
      const int byte = row*256 + col8*16;
      *(short8*)((char*)wl + (byte ^ ((row&7)<<4))) = v;
    }
  }
  __syncthreads();

  gemm64<false>(mv, bk, g, bln, nullptr, ropetab, kout, wl, block0);
  gemm64<false>(mv, bk, g, bln, nullptr, ropetab, kout, wl, block0 + 64);

  __syncthreads();   // all MFMA reads of wl done

  // restage 128 mv rows (fp32 -> fp16, swizzled) into wl
  {
    const float4* xg = (const float4*)(mv + (size_t)block0 * D);
    #pragma unroll
    for (int it = 0; it < 8; ++it) {
      const int idx = tid + 256*it;          // half8 index, 2048 total
      const int row = idx >> 4, col8 = idx & 15;
      const float4 f0 = xg[idx*2], f1 = xg[idx*2+1];
      _Float16 h[8] = {(_Float16)f0.x,(_Float16)f0.y,(_Float16)f0.z,(_Float16)f0.w,
                       (_Float16)f1.x,(_Float16)f1.y,(_Float16)f1.z,(_Float16)f1.w};
      const int byte = row*256 + col8*16;
      *(half8*)((char*)wl + (byte ^ ((row&7)<<4))) = *(half8*)h;
    }
  }
  __syncthreads();

  // emit V^T: thread (d, ph) handles p-range ph*64..ph*64+63 of this tile
  {
    const int bt2 = block0 >> 10;
    const int p0  = block0 & (P-1);
    const int d   = tid & 127, ph = tid >> 7;
    #pragma unroll
    for (int seg = 0; seg < 2; ++seg) {
      short hv[32];
      #pragma unroll
      for (int i = 0; i < 32; ++i) {
        const int pl2 = ph*64 + seg*32 + i;
        const int byte = pl2*256 + d*2;
        hv[i] = *(const short*)((const char*)wl + (byte ^ ((pl2&7)<<4)));
      }
      short8* dst = (short8*)(vt + ((size_t)bt2*D + d)*P + p0 + ph*64 + seg*32);
      #pragma unroll
      for (int i = 0; i < 4; ++i) dst[i] = ((short8*)hv)[i];
    }
  }
}

// ---------------------------------------------------------------------------
// Q path: validated 64-row kernel (W staged, gemm64, no V^T).
// ---------------------------------------------------------------------------
__global__ __launch_bounds__(256)
void proj_q(const float* __restrict__ t,
            const _Float16* __restrict__ w16q,
            const float* __restrict__ bq,
            const float* __restrict__ g,
            const float* __restrict__ bln,
            const int*   __restrict__ positions,
            const float2* __restrict__ ropetab,
            _Float16* __restrict__ qout)
{
  const int tid = threadIdx.x;
  __shared__ _Float16 wl[128*128];
  {
    const short8* wg = (const short8*)w16q;
    #pragma unroll
    for (int it = 0; it < 8; ++it) {
      const int idx = tid + 256*it;
      const int row = idx >> 4, col8 = idx & 15;
      const short8 v = wg[idx];
      const int byte = row*256 + col8*16;
      *(short8*)((char*)wl + (byte ^ ((row&7)<<4))) = v;
    }
  }
  __syncthreads();
  gemm64<true>(t, bq, g, bln, positions, ropetab, qout, wl, blockIdx.x * 64);
}

// ---------------------------------------------------------------------------
// Flash attention, fixed-max softmax (m=4), 512 blocks, direct out write.
// RACE-SAFE (R12 fix): pl and o16 are separate LDS buffers; a barrier orders
// loop completion before the epilogue writes.
// Bound proof as R9: P = exp(s-4) in [2.2e-7, 1500], fp16-safe, lsum > 0.
// ---------------------------------------------------------------------------
__global__ __launch_bounds__(256)
void attn_mfma(const _Float16* __restrict__ q,
               const _Float16* __restrict__ k,
               const _Float16* __restrict__ vt,   // (BT, D, P)
               const int* __restrict__ positions,
               float* __restrict__ out)
{
  const int bt  = blockIdx.x & (BT-1);   // same-bt blocks -> same XCD
  const int qq  = blockIdx.x >> 7;
  const int tid = threadIdx.x;
  const int w   = tid >> 6, lane = tid & 63;
  const int g   = lane >> 4, c = lane & 15;

  __shared__ _Float16 pl[4][16][88];      // 11 KB  (loop-live)
  __shared__ _Float16 o16[4][16][136];    // 17.4 KB (epilogue-live)
  __shared__ float    l_lds[4][16];

  const _Float16* qrow = q + (size_t)(bt*M + qq*16 + c) * D + g*8;
  half8 aq[4];
  #pragma unroll
  for (int ks = 0; ks < 4; ++ks) aq[ks] = *(const half8*)(qrow + ks*32);

  float ph[4], pw[4];
  #pragma unroll
  for (int r = 0; r < 4; ++r) {
    const int pos = positions[bt*M + qq*16 + g*4 + r];
    ph[r] = (float)(pos >> 5); pw[r] = (float)(pos & 31);
  }

  float lsum[4] = {0.f, 0.f, 0.f, 0.f};
  floatx4 oacc[8];
  #pragma unroll
  for (int dt = 0; dt < 8; ++dt) oacc[dt] = (floatx4){0.f,0.f,0.f,0.f};

  const _Float16* kb = k  + ((size_t)bt * P) * D;
  const _Float16* vb = vt + ((size_t)bt * D) * P;

  for (int t = 0; t < 4; ++t) {
    const int p0 = w*256 + t*64;

    floatx4 s[4];
    #pragma unroll
    for (int pt = 0; pt < 4; ++pt) {
      floatx4 a4 = (floatx4){0.f,0.f,0.f,0.f};
      const _Float16* krow = kb + (size_t)(p0 + pt*16 + c) * D + g*8;
      #pragma unroll
      for (int ks = 0; ks < 4; ++ks)
        a4 = __builtin_amdgcn_mfma_f32_16x16x32_f16(
                 aq[ks], *(const half8*)(krow + ks*32), a4, 0, 0, 0);
      s[pt] = a4;
    }

    #pragma unroll
    for (int pt = 0; pt < 4; ++pt) {
      const int pp = p0 + pt*16 + c;
      const float hh = (float)(pp >> 5), ww = (float)(pp & 31);
      #pragma unroll
      for (int r = 0; r < 4; ++r) {
        const float dx = ph[r] - hh, dy = pw[r] - ww;
        const float sv = s[pt][r]*SCALE - 0.125f*sqrtf(dx*dx + dy*dy);
        const float e  = __expf(sv - 4.0f);
        const _Float16 eh = (_Float16)e;
        pl[w][g*4 + r][pt*16 + c] = eh;
        lsum[r] += (float)eh;
      }
    }

    #pragma unroll
    for (int ks = 0; ks < 2; ++ks) {
      const half8 pa = *(const half8*)(&pl[w][c][ks*32 + g*8]);
      #pragma unroll
      for (int dt = 0; dt < 8; ++dt) {
        const half8 bv = *(const half8*)(vb + (size_t)(dt*16 + c)*P
                                            + p0 + ks*32 + g*8);
        oacc[dt] = __builtin_amdgcn_mfma_f32_16x16x32_f16(pa, bv, oacc[dt], 0,0,0);
      }
    }
  }

  __syncthreads();   // race fix: all waves' pl reads complete before epilogue

  #pragma unroll
  for (int r = 0; r < 4; ++r) {
    #pragma unroll
    for (int off = 1; off <= 8; off <<= 1)
      lsum[r] += __shfl_xor(lsum[r], off);
  }
  if (c == 0) {
    #pragma unroll
    for (int r = 0; r < 4; ++r) l_lds[w][g*4 + r] = lsum[r];
  }

  #pragma unroll
  for (int dt = 0; dt < 8; ++dt)
    #pragma unroll
    for (int r = 0; r < 4; ++r)
      o16[w][g*4 + r][dt*16 + c] = (_Float16)oacc[dt][r];
  __syncthreads();

  const int qi = tid >> 4, dg = tid & 15;
  const float L = l_lds[0][qi] + l_lds[1][qi] + l_lds[2][qi] + l_lds[3][qi];
  const float inv = 1.0f / L;
  float a2[8] = {0.f,0.f,0.f,0.f,0.f,0.f,0.f,0.f};
  #pragma unroll
  for (int w2 = 0; w2 < 4; ++w2) {
    const half8 ov = *(const half8*)(&o16[w2][qi][dg*8]);
    #pragma unroll
    for (int dd = 0; dd < 8; ++dd) a2[dd] += (float)ov[dd];
  }
  float* orow = out + (size_t)(bt*M + qq*16 + qi) * D + dg*8;
  #pragma unroll
  for (int dd = 0; dd < 8; ++dd) orow[dd] = a2[dd] * inv;
}

// ---------------------------------------------------------------------------
extern "C" void kernel_launch(void* const* d_in, const int* in_sizes, int n_in,
                              void* d_out, int out_size, void* d_ws, size_t ws_size,
                              hipStream_t stream) {
  const float* t    = (const float*)d_in[0];
  const float* mv   = (const float*)d_in[1];
  const int*   pos  = (const int*)  d_in[2];
  const float* Wq   = (const float*)d_in[3];
  const float* bq   = (const float*)d_in[4];
  const float* Wk   = (const float*)d_in[5];
  const float* bk   = (const float*)d_in[6];
  const float* ln_g = (const float*)d_in[7];
  const float* ln_b = (const float*)d_in[8];
  float* out = (float*)d_out;

  _Float16* qbuf = (_Float16*)d_ws;                 // 1,048,576 halfs
  _Float16* kbuf = qbuf + (size_t)BT*M*D;           // 16,777,216
  _Float16* vtbf = kbuf + (size_t)BT*P*D;           // 16,777,216
  _Float16* w16q = vtbf + (size_t)BT*P*D;           // 16,384
  _Float16* w16k = w16q + D*D;                      // 16,384
  float2*   rtab = (float2*)(w16k + D*D);           // 1,024 float2

  prep<<<33, 1024, 0, stream>>>(Wq, Wk, w16q, w16k, rtab);
  proj_k128<<<BT*P/128, 256, 0, stream>>>(mv, w16k, bk, ln_g, ln_b,
                                          rtab, kbuf, vtbf);
  proj_q<<<BT*M/64, 256, 0, stream>>>(t, w16q, bq, ln_g, ln_b, pos, rtab, qbuf);
  attn_mfma<<<512, 256, 0, stream>>>(qbuf, kbuf, vtbf, pos, out);
}

// Round 14
// 100.768 us; speedup vs baseline: 1.3252x; 1.3252x over previous
//
#include <hip/hip_runtime.h>
#include <math.h>

#define D   128
#define HP  32
#define WP  32
#define M   64
#define Bb  8
#define Tt  16
#define P   (HP*WP)      // 1024
#define BT  (Bb*Tt)      // 128
#define EPSF 1e-5f
#define SCALE 0.08838834764831845f   // 1/sqrt(128)

typedef __attribute__((ext_vector_type(8))) _Float16 half8;
typedef __attribute__((ext_vector_type(8))) short    short8;
typedef __attribute__((ext_vector_type(4))) float    floatx4;

// ---------------------------------------------------------------------------
// Prep: RoPE cos/sin table + Wq/Wk fp32->fp16.  (validated)
// ---------------------------------------------------------------------------
__global__ __launch_bounds__(1024)
void prep(const float* __restrict__ Wq, const float* __restrict__ Wk,
          _Float16* __restrict__ W16q, _Float16* __restrict__ W16k,
          float2* __restrict__ ropetab)
{
  const int b = blockIdx.x, t = threadIdx.x;
  if (b == 0) {
    const int gq = t >> 5, coord = t & 31;
    const float theta = __powf(100.0f, -4.0f*(float)(gq+1)/128.0f);
    float s, c;
    __sincosf(theta*(float)coord, &s, &c);
    ropetab[t] = make_float2(c, s);
  } else if (b <= 16) {
    const int i = (b-1)*1024 + t;
    W16q[i] = (_Float16)Wq[i];
  } else {
    const int i = (b-17)*1024 + t;
    W16k[i] = (_Float16)Wk[i];
  }
}

// ---------------------------------------------------------------------------
// K-path projection, 64 rows/block (R10 structure), ALL global loads hoisted
// to the kernel top (W, A-frags, V^T-restage) so their HBM latency overlaps
// the W-stage and MFMA phases instead of sitting serially in the chain.
// Math/store paths byte-identical to validated R10 proj_reg<false>.
// ---------------------------------------------------------------------------
__global__ __launch_bounds__(256)
void proj_k64(const float* __restrict__ mv,
              const _Float16* __restrict__ w16k,
              const float* __restrict__ bk,
              const float* __restrict__ g,
              const float* __restrict__ bln,
              const float2* __restrict__ ropetab,
              _Float16* __restrict__ kout,
              _Float16* __restrict__ vt)
{
  const int tid = threadIdx.x;
  const int w = tid >> 6, lane = tid & 63;
  const int gg = lane >> 4, c = lane & 15;
  const int block0 = blockIdx.x * 64;

  __shared__ _Float16 wl[128*128];  // W (32KB); first 16KB reused for V^T tile

  // ---- issue ALL global loads up front (independent of LDS) ----
  short8 wreg[8];
  {
    const short8* wg = (const short8*)w16k;
    #pragma unroll
    for (int it = 0; it < 8; ++it) wreg[it] = wg[tid + 256*it];
  }
  float4 af[8];
  {
    const float* xr = mv + (size_t)(block0 + w*16 + c) * D;
    #pragma unroll
    for (int ks = 0; ks < 4; ++ks) {
      af[2*ks]   = *(const float4*)(xr + ks*32 + gg*8);
      af[2*ks+1] = *(const float4*)(xr + ks*32 + gg*8 + 4);
    }
  }
  float4 vf[8];
  {
    const float4* xg = (const float4*)(mv + (size_t)block0 * D);
    #pragma unroll
    for (int it = 0; it < 4; ++it) {
      const int idx = tid + 256*it;
      vf[2*it]   = xg[idx*2];
      vf[2*it+1] = xg[idx*2+1];
    }
  }

  // ---- stage W to LDS (swizzled, validated code) ----
  #pragma unroll
  for (int it = 0; it < 8; ++it) {
    const int idx = tid + 256*it;
    const int row = idx >> 4, col8 = idx & 15;
    const int byte = row*256 + col8*16;
    *(short8*)((char*)wl + (byte ^ ((row&7)<<4))) = wreg[it];
  }
  __syncthreads();

  // ---- A fragments from preloaded regs ----
  half8 aq[4];
  #pragma unroll
  for (int ks = 0; ks < 4; ++ks) {
    const float4 f0 = af[2*ks], f1 = af[2*ks+1];
    _Float16 h[8] = {(_Float16)f0.x,(_Float16)f0.y,(_Float16)f0.z,(_Float16)f0.w,
                     (_Float16)f1.x,(_Float16)f1.y,(_Float16)f1.z,(_Float16)f1.w};
    aq[ks] = *(half8*)h;
  }

  // ---- MFMA ----
  floatx4 acc[8];
  #pragma unroll
  for (int jt = 0; jt < 8; ++jt) {
    floatx4 a4 = (floatx4){0.f,0.f,0.f,0.f};
    #pragma unroll
    for (int ks = 0; ks < 4; ++ks) {
      const int brow = jt*16 + c;
      const int byte = brow*256 + (gg*8 + ks*32)*2;
      const half8 bf = *(const half8*)((const char*)wl + (byte ^ ((brow&7)<<4)));
      a4 = __builtin_amdgcn_mfma_f32_16x16x32_f16(aq[ks], bf, a4, 0, 0, 0);
    }
    acc[jt] = a4;
  }

  __syncthreads();   // all MFMA reads of wl complete

  // ---- V^T: store preloaded mv tile (fp16, swizzled) into dead wl space ----
  #pragma unroll
  for (int it = 0; it < 4; ++it) {
    const int idx = tid + 256*it;
    const int row = idx >> 4, col8 = idx & 15;
    const float4 f0 = vf[2*it], f1 = vf[2*it+1];
    _Float16 h[8] = {(_Float16)f0.x,(_Float16)f0.y,(_Float16)f0.z,(_Float16)f0.w,
                     (_Float16)f1.x,(_Float16)f1.y,(_Float16)f1.z,(_Float16)f1.w};
    const int byte = row*256 + col8*16;
    *(half8*)((char*)wl + (byte ^ ((row&7)<<4))) = *(half8*)h;
  }
  __syncthreads();

  // ---- emit V^T (validated R10 code) ----
  {
    const int bt2 = block0 >> 10;
    const int p0  = block0 & (P-1);
    const int dd  = tid & 127, ph2 = tid >> 7;
    short hv[32];
    #pragma unroll
    for (int i = 0; i < 32; ++i) {
      const int pl2 = ph2*32 + i;
      const int byte = pl2*256 + dd*2;
      hv[i] = *(const short*)((const char*)wl + (byte ^ ((pl2&7)<<4)));
    }
    short8* dst = (short8*)(vt + ((size_t)bt2*D + dd)*P + p0 + ph2*32);
    #pragma unroll
    for (int i = 0; i < 4; ++i) dst[i] = ((short8*)hv)[i];
  }

  // ---- bias + RoPE + LN in registers (validated R8/R10 code, K path) ----
  const int rr = c & 3;
  int coordv[4];
  #pragma unroll
  for (int r = 0; r < 4; ++r) {
    const int grow = block0 + w*16 + gg*4 + r;
    const int p = grow & (P-1);
    const int hh = p >> 5, ww = p & 31;
    coordv[r] = (rr & 1) ? ww : hh;
  }

  float fin[8][4];
  float s1[4] = {0.f,0.f,0.f,0.f}, s2[4] = {0.f,0.f,0.f,0.f};
  #pragma unroll
  for (int jt = 0; jt < 8; ++jt) {
    const float bj = bk[jt*16 + c];
    const int gq = jt*4 + (c >> 2);
    #pragma unroll
    for (int r = 0; r < 4; ++r) {
      const float val = acc[jt][r] + bj;
      const float2 tt = ropetab[gq*32 + coordv[r]];
      const float p2 = __shfl_xor(val, 2);
      const float f1v = (rr & 1) ? (val*tt.x + p2*tt.y)
                                 : (val*tt.x - p2*tt.y);
      const float g2 = __shfl_xor(f1v, 2);
      const float fn = (rr >= 2)
          ? ((rr & 1) ? (val*tt.x + g2*tt.y) : (val*tt.x - g2*tt.y))
          : f1v;
      fin[jt][r] = fn;
      s1[r] += fn;
      s2[r] += fn*fn;
    }
  }

  #pragma unroll
  for (int r = 0; r < 4; ++r) {
    #pragma unroll
    for (int off = 1; off <= 8; off <<= 1) {
      s1[r] += __shfl_xor(s1[r], off);
      s2[r] += __shfl_xor(s2[r], off);
    }
  }

  #pragma unroll
  for (int r = 0; r < 4; ++r) {
    const float mu   = s1[r] * (1.f/128.f);
    const float var  = s2[r] * (1.f/128.f) - mu*mu;
    const float rinv = rsqrtf(var + EPSF);
    const int grow = block0 + w*16 + gg*4 + r;
    _Float16* yo = kout + (size_t)grow * D;
    #pragma unroll
    for (int jt = 0; jt < 8; ++jt) {
      const int col = jt*16 + c;
      const float nv = (fin[jt][r] - mu) * rinv * g[col] + bln[col];
      yo[col] = (_Float16)nv;
    }
  }
}

// ---------------------------------------------------------------------------
// Q path: validated R13 kernel (W staged, 64-row gemm, no V^T).
// ---------------------------------------------------------------------------
__global__ __launch_bounds__(256)
void proj_q(const float* __restrict__ t,
            const _Float16* __restrict__ w16q,
            const float* __restrict__ bq,
            const float* __restrict__ g,
            const float* __restrict__ bln,
            const int*   __restrict__ positions,
            const float2* __restrict__ ropetab,
            _Float16* __restrict__ qout)
{
  const int tid = threadIdx.x;
  const int w = tid >> 6, lane = tid & 63;
  const int gg = lane >> 4, c = lane & 15;
  const int block0 = blockIdx.x * 64;

  __shared__ _Float16 wl[128*128];
  {
    const short8* wg = (const short8*)w16q;
    #pragma unroll
    for (int it = 0; it < 8; ++it) {
      const int idx = tid + 256*it;
      const int row = idx >> 4, col8 = idx & 15;
      const short8 v = wg[idx];
      const int byte = row*256 + col8*16;
      *(short8*)((char*)wl + (byte ^ ((row&7)<<4))) = v;
    }
  }
  __syncthreads();

  const float* xr = t + (size_t)(block0 + w*16 + c) * D;
  half8 aq[4];
  #pragma unroll
  for (int ks = 0; ks < 4; ++ks) {
    const float4 f0 = *(const float4*)(xr + ks*32 + gg*8);
    const float4 f1 = *(const float4*)(xr + ks*32 + gg*8 + 4);
    _Float16 h[8] = {(_Float16)f0.x,(_Float16)f0.y,(_Float16)f0.z,(_Float16)f0.w,
                     (_Float16)f1.x,(_Float16)f1.y,(_Float16)f1.z,(_Float16)f1.w};
    aq[ks] = *(half8*)h;
  }

  floatx4 acc[8];
  #pragma unroll
  for (int jt = 0; jt < 8; ++jt) {
    floatx4 a4 = (floatx4){0.f,0.f,0.f,0.f};
    #pragma unroll
    for (int ks = 0; ks < 4; ++ks) {
      const int brow = jt*16 + c;
      const int byte = brow*256 + (gg*8 + ks*32)*2;
      const half8 bf = *(const half8*)((const char*)wl + (byte ^ ((brow&7)<<4)));
      a4 = __builtin_amdgcn_mfma_f32_16x16x32_f16(aq[ks], bf, a4, 0, 0, 0);
    }
    acc[jt] = a4;
  }

  const int rr = c & 3;
  int coordv[4];
  #pragma unroll
  for (int r = 0; r < 4; ++r) {
    const int grow = block0 + w*16 + gg*4 + r;
    const int pos = positions[grow];
    const int hh = pos >> 5, ww = pos & 31;
    coordv[r] = (rr & 1) ? ww : hh;
  }

  float fin[8][4];
  float s1[4] = {0.f,0.f,0.f,0.f}, s2[4] = {0.f,0.f,0.f,0.f};
  #pragma unroll
  for (int jt = 0; jt < 8; ++jt) {
    const float bj = bq[jt*16 + c];
    const int gq = jt*4 + (c >> 2);
    #pragma unroll
    for (int r = 0; r < 4; ++r) {
      const float val = acc[jt][r] + bj;
      const float2 tt = ropetab[gq*32 + coordv[r]];
      const float p2 = __shfl_xor(val, 2);
      const float f1v = (rr & 1) ? (val*tt.x + p2*tt.y)
                                 : (val*tt.x - p2*tt.y);
      const float g2 = __shfl_xor(f1v, 2);
      const float fn = (rr >= 2)
          ? ((rr & 1) ? (val*tt.x + g2*tt.y) : (val*tt.x - g2*tt.y))
          : f1v;
      fin[jt][r] = fn;
      s1[r] += fn;
      s2[r] += fn*fn;
    }
  }

  #pragma unroll
  for (int r = 0; r < 4; ++r) {
    #pragma unroll
    for (int off = 1; off <= 8; off <<= 1) {
      s1[r] += __shfl_xor(s1[r], off);
      s2[r] += __shfl_xor(s2[r], off);
    }
  }

  #pragma unroll
  for (int r = 0; r < 4; ++r) {
    const float mu   = s1[r] * (1.f/128.f);
    const float var  = s2[r] * (1.f/128.f) - mu*mu;
    const float rinv = rsqrtf(var + EPSF);
    const int grow = block0 + w*16 + gg*4 + r;
    _Float16* yo = qout + (size_t)grow * D;
    #pragma unroll
    for (int jt = 0; jt < 8; ++jt) {
      const int col = jt*16 + c;
      const float nv = (fin[jt][r] - mu) * rinv * g[col] + bln[col];
      yo[col] = (_Float16)nv;
    }
  }
}

// ---------------------------------------------------------------------------
// Flash attention, fixed-max softmax (m=4), 512 blocks, race-safe (validated
// R13: separate pl/o16 + barrier before epilogue).
// Bound proof as R9: P = exp(s-4) in [2.2e-7, 1500], fp16-safe, lsum > 0.
// ---------------------------------------------------------------------------
__global__ __launch_bounds__(256)
void attn_mfma(const _Float16* __restrict__ q,
               const _Float16* __restrict__ k,
               const _Float16* __restrict__ vt,   // (BT, D, P)
               const int* __restrict__ positions,
               float* __restrict__ out)
{
  const int bt  = blockIdx.x & (BT-1);
  const int qq  = blockIdx.x >> 7;
  const int tid = threadIdx.x;
  const int w   = tid >> 6, lane = tid & 63;
  const int g   = lane >> 4, c = lane & 15;

  __shared__ _Float16 pl[4][16][88];
  __shared__ _Float16 o16[4][16][136];
  __shared__ float    l_lds[4][16];

  const _Float16* qrow = q + (size_t)(bt*M + qq*16 + c) * D + g*8;
  half8 aq[4];
  #pragma unroll
  for (int ks = 0; ks < 4; ++ks) aq[ks] = *(const half8*)(qrow + ks*32);

  float ph[4], pw[4];
  #pragma unroll
  for (int r = 0; r < 4; ++r) {
    const int pos = positions[bt*M + qq*16 + g*4 + r];
    ph[r] = (float)(pos >> 5); pw[r] = (float)(pos & 31);
  }

  float lsum[4] = {0.f, 0.f, 0.f, 0.f};
  floatx4 oacc[8];
  #pragma unroll
  for (int dt = 0; dt < 8; ++dt) oacc[dt] = (floatx4){0.f,0.f,0.f,0.f};

  const _Float16* kb = k  + ((size_t)bt * P) * D;
  const _Float16* vb = vt + ((size_t)bt * D) * P;

  for (int t = 0; t < 4; ++t) {
    const int p0 = w*256 + t*64;

    floatx4 s[4];
    #pragma unroll
    for (int pt = 0; pt < 4; ++pt) {
      floatx4 a4 = (floatx4){0.f,0.f,0.f,0.f};
      const _Float16* krow = kb + (size_t)(p0 + pt*16 + c) * D + g*8;
      #pragma unroll
      for (int ks = 0; ks < 4; ++ks)
        a4 = __builtin_amdgcn_mfma_f32_16x16x32_f16(
                 aq[ks], *(const half8*)(krow + ks*32), a4, 0, 0, 0);
      s[pt] = a4;
    }

    #pragma unroll
    for (int pt = 0; pt < 4; ++pt) {
      const int pp = p0 + pt*16 + c;
      const float hh = (float)(pp >> 5), ww = (float)(pp & 31);
      #pragma unroll
      for (int r = 0; r < 4; ++r) {
        const float dx = ph[r] - hh, dy = pw[r] - ww;
        const float sv = s[pt][r]*SCALE - 0.125f*sqrtf(dx*dx + dy*dy);
        const float e  = __expf(sv - 4.0f);
        const _Float16 eh = (_Float16)e;
        pl[w][g*4 + r][pt*16 + c] = eh;
        lsum[r] += (float)eh;
      }
    }

    #pragma unroll
    for (int ks = 0; ks < 2; ++ks) {
      const half8 pa = *(const half8*)(&pl[w][c][ks*32 + g*8]);
      #pragma unroll
      for (int dt = 0; dt < 8; ++dt) {
        const half8 bv = *(const half8*)(vb + (size_t)(dt*16 + c)*P
                                            + p0 + ks*32 + g*8);
        oacc[dt] = __builtin_amdgcn_mfma_f32_16x16x32_f16(pa, bv, oacc[dt], 0,0,0);
      }
    }
  }

  __syncthreads();   // race fix: all waves' pl reads complete before epilogue

  #pragma unroll
  for (int r = 0; r < 4; ++r) {
    #pragma unroll
    for (int off = 1; off <= 8; off <<= 1)
      lsum[r] += __shfl_xor(lsum[r], off);
  }
  if (c == 0) {
    #pragma unroll
    for (int r = 0; r < 4; ++r) l_lds[w][g*4 + r] = lsum[r];
  }

  #pragma unroll
  for (int dt = 0; dt < 8; ++dt)
    #pragma unroll
    for (int r = 0; r < 4; ++r)
      o16[w][g*4 + r][dt*16 + c] = (_Float16)oacc[dt][r];
  __syncthreads();

  const int qi = tid >> 4, dg = tid & 15;
  const float L = l_lds[0][qi] + l_lds[1][qi] + l_lds[2][qi] + l_lds[3][qi];
  const float inv = 1.0f / L;
  float a2[8] = {0.f,0.f,0.f,0.f,0.f,0.f,0.f,0.f};
  #pragma unroll
  for (int w2 = 0; w2 < 4; ++w2) {
    const half8 ov = *(const half8*)(&o16[w2][qi][dg*8]);
    #pragma unroll
    for (int dd = 0; dd < 8; ++dd) a2[dd] += (float)ov[dd];
  }
  float* orow = out + (size_t)(bt*M + qq*16 + qi) * D + dg*8;
  #pragma unroll
  for (int dd = 0; dd < 8; ++dd) orow[dd] = a2[dd] * inv;
}

// ---------------------------------------------------------------------------
extern "C" void kernel_launch(void* const* d_in, const int* in_sizes, int n_in,
                              void* d_out, int out_size, void* d_ws, size_t ws_size,
                              hipStream_t stream) {
  const float* t    = (const float*)d_in[0];
  const float* mv   = (const float*)d_in[1];
  const int*   pos  = (const int*)  d_in[2];
  const float* Wq   = (const float*)d_in[3];
  const float* bq   = (const float*)d_in[4];
  const float* Wk   = (const float*)d_in[5];
  const float* bk   = (const float*)d_in[6];
  const float* ln_g = (const float*)d_in[7];
  const float* ln_b = (const float*)d_in[8];
  float* out = (float*)d_out;

  _Float16* qbuf = (_Float16*)d_ws;                 // 1,048,576 halfs
  _Float16* kbuf = qbuf + (size_t)BT*M*D;           // 16,777,216
  _Float16* vtbf = kbuf + (size_t)BT*P*D;           // 16,777,216
  _Float16* w16q = vtbf + (size_t)BT*P*D;           // 16,384
  _Float16* w16k = w16q + D*D;                      // 16,384
  float2*   rtab = (float2*)(w16k + D*D);           // 1,024 float2

  prep<<<33, 1024, 0, stream>>>(Wq, Wk, w16q, w16k, rtab);
  proj_k64<<<BT*P/64, 256, 0, stream>>>(mv, w16k, bk, ln_g, ln_b,
                                        rtab, kbuf, vtbf);
  proj_q<<<BT*M/64, 256, 0, stream>>>(t, w16q, bq, ln_g, ln_b, pos, rtab, qbuf);
  attn_mfma<<<512, 256, 0, stream>>>(qbuf, kbuf, vtbf, pos, out);
}